// Round 14
// baseline (276.858 us; speedup 1.0000x reference)
//
#include <hip/hip_runtime.h>

#define N_NODES 50000
#define E_EDGES 800000
#define E2      (2 * E_EDGES)
#define D_DIM   200
#define C_CLS   10
#define NB_BUCKET 196                        // buckets of 256 rows (r>>8)
#define BATCH     4096                       // edges per scatter block
#define NB_SCATTER ((E2 + BATCH - 1) / BATCH)          // 391
#define NB_CONV    ((N_NODES * D_DIM / 4 + 255) / 256) // 9766
#define CAP       12288                      // stage slots/bucket (mean 8163, >45 sigma)

static __device__ __forceinline__ unsigned f2bf(float f) {
    unsigned u = __float_as_uint(f);
    return (u + 0x7FFFu + ((u >> 16) & 1u)) >> 16;     // RNE, low 16 bits
}
static __device__ __forceinline__ float bf_lo(unsigned u) {
    return __uint_as_float(u << 16);
}
static __device__ __forceinline__ float bf_hi(unsigned u) {
    return __uint_as_float(u & 0xFFFF0000u);
}

// ---------------------------------------------------------------------------
// Fused convert + scatter. Scatter blocks now bucket-sort their BATCH records
// in LDS and write stage runs with coalesced segment copies (was: 64 scattered
// 8 B transactions per wave). Convert blocks stream W0 -> bf16 unchanged.
// bcur (+ticket) zeroed by hipMemsetAsync beforehand.
// ---------------------------------------------------------------------------
__global__ __launch_bounds__(256) void convert_scatter_kernel(
        const float* __restrict__ W0, unsigned short* __restrict__ W0h,
        const int* __restrict__ rows0, const int* __restrict__ cols0,
        const float* __restrict__ vals0,
        const int* __restrict__ rows1, const int* __restrict__ cols1,
        const float* __restrict__ vals1,
        int* __restrict__ bcur,
        int2* __restrict__ stage) {
    __shared__ int cntL[256];              // bucket counts (196 used)
    __shared__ int lofs[256];              // local exclusive offsets
    __shared__ int baseG[NB_BUCKET];       // global run bases
    __shared__ int cur[NB_BUCKET];         // local cursors
    __shared__ int ws4[4];
    __shared__ int2 recL2[BATCH];          // 32 KB, bucket-sorted records

    if (blockIdx.x >= NB_SCATTER) {
        // ---- convert path (streaming) ----
        int i = ((blockIdx.x - NB_SCATTER) * 256 + threadIdx.x) * 4;
        if (i < N_NODES * D_DIM) {
            float4 f = *(const float4*)(W0 + i);
            uint2 p;
            p.x = f2bf(f.x) | (f2bf(f.y) << 16);
            p.y = f2bf(f.z) | (f2bf(f.w) << 16);
            *(uint2*)(W0h + i) = p;
        }
        return;
    }

    // ---- scatter path ----
    const int tid = threadIdx.x;
    const int lane = tid & 63;
    const int w = tid >> 6;
    const int e0 = blockIdx.x * BATCH;
    const int m = min(BATCH, E2 - e0);     // records handled by this block

    cntL[tid] = 0;
    __syncthreads();

    // Pass 1: count per bucket.
#pragma unroll
    for (int k = 0; k < BATCH / 256; ++k) {
        int idx = k * 256 + tid;
        int e = e0 + idx;
        if (idx < m) {
            int r = (e < E_EDGES) ? rows0[e] : rows1[e - E_EDGES];
            atomicAdd(&cntL[r >> 8], 1);
        }
    }
    __syncthreads();

    // Block exclusive scan of cntL -> lofs (cntL preserved).
    int v = cntL[tid];
    const int orig = v;
#pragma unroll
    for (int off = 1; off < 64; off <<= 1) {
        int t = __shfl_up(v, off, 64);
        if (lane >= off) v += t;
    }
    if (lane == 63) ws4[w] = v;
    __syncthreads();
    if (tid == 0) {
        int s = 0;
#pragma unroll
        for (int k = 0; k < 4; ++k) { int t = ws4[k]; ws4[k] = s; s += t; }
    }
    __syncthreads();
    lofs[tid] = v + ws4[w] - orig;
    __syncthreads();

    // Reserve global runs, init local cursors.
    if (tid < NB_BUCKET) {
        int c = cntL[tid];
        baseG[tid] = (c > 0) ? atomicAdd(&bcur[tid], c) : 0;
        cur[tid] = lofs[tid];
    }
    __syncthreads();

    // Pass 2: re-read edges (L2-warm), place bucket-sorted into LDS.
#pragma unroll
    for (int k = 0; k < BATCH / 256; ++k) {
        int idx = k * 256 + tid;
        int e = e0 + idx;
        if (idx < m) {
            int r, c;
            float val;
            if (e < E_EDGES) {
                r = rows0[e]; c = cols0[e]; val = vals0[e];
            } else {
                int e1 = e - E_EDGES;
                r = rows1[e1]; c = cols1[e1]; val = vals1[e1];
            }
            int p = atomicAdd(&cur[r >> 8], 1);
            recL2[p] = make_int2((int)((unsigned)r | ((unsigned)c << 16)),
                                 __float_as_int(val));
        }
    }
    __syncthreads();

    // Pass 3: coalesced copy-out. Bucket of slot p via binary search over lofs
    // (last b with lofs[b] <= p); consecutive p -> consecutive stage addrs.
    for (int p = tid; p < m; p += 256) {
        int lo = 0, hi = NB_BUCKET - 1;
        while (lo < hi) {
            int mid = (lo + hi + 1) >> 1;
            if (lofs[mid] <= p) lo = mid; else hi = mid - 1;
        }
        stage[(size_t)lo * CAP + baseG[lo] + (p - lofs[lo])] = recL2[p];
    }
}

// ---------------------------------------------------------------------------
// Build CSR (ticket-based, r13-proven) with LDS-staged cv4 writes: place into
// cv4L at local positions (LDS scatter), then linear coalesced copy to cv4.
// ---------------------------------------------------------------------------
__global__ __launch_bounds__(256) void build_csr_kernel(
        const int* __restrict__ bcur,
        const int2* __restrict__ stage,
        int* __restrict__ ticket,
        int2* __restrict__ rowseg,
        unsigned* __restrict__ cv4) {
    __shared__ int hist[256];
    __shared__ int lcur[256];
    __shared__ int ws4[4];
    __shared__ int sbase;
    __shared__ int stot;
    __shared__ unsigned cv4L[CAP];          // 48 KB
    const int b = blockIdx.x;
    const int tid = threadIdx.x;
    const int lane = tid & 63;
    const int w = tid >> 6;
    hist[tid] = 0;
    __syncthreads();

    const int n = bcur[b];
    const int2* __restrict__ sp = stage + (size_t)b * CAP;
    for (int i = tid; i < n; i += 256)
        atomicAdd(&hist[(unsigned)sp[i].x & 255u], 1);
    __syncthreads();

    int v = hist[tid];
    const int orig = v;
#pragma unroll
    for (int off = 1; off < 64; off <<= 1) {
        int t = __shfl_up(v, off, 64);
        if (lane >= off) v += t;
    }
    if (lane == 63) ws4[w] = v;
    __syncthreads();
    if (tid == 0) {
        int s = 0;
#pragma unroll
        for (int k = 0; k < 4; ++k) { int t = ws4[k]; ws4[k] = s; s += t; }
    }
    __syncthreads();
    v += ws4[w];                            // inclusive over 256 rows

    if (tid == 255) {
        stot = v;
        sbase = atomicAdd(ticket, v);       // reserve [sbase, sbase+stot)
    }
    __syncthreads();

    const int row = (b << 8) + tid;
    if (row < N_NODES) rowseg[row] = make_int2(sbase + v - orig, orig);
    lcur[tid] = v - orig;                   // local exclusive offset
    __syncthreads();

    // Place into LDS at local positions.
    for (int i = tid; i < n; i += 256) {
        int2 rec = sp[i];
        unsigned u = (unsigned)rec.x;
        int pos = atomicAdd(&lcur[u & 255u], 1);
        cv4L[pos] = (u & 0xFFFF0000u) | f2bf(__int_as_float(rec.y));
    }
    __syncthreads();

    // Linear coalesced copy-out.
    for (int i = tid; i < stot; i += 256)
        cv4[sbase + i] = cv4L[i];
}

// ---------------------------------------------------------------------------
// Fused layer 0 (r9/r11/r13-proven unroll-8, rowseg): per node n,
//   t = relu( sum_e v_e * W0h[c_e,:] + s0 * W0h[n,:] ); g[n,:] = t @ W1
// ---------------------------------------------------------------------------
__global__ __launch_bounds__(256) void spmm_layer0_fused_kernel(
        const int2* __restrict__ rowseg,
        const unsigned* __restrict__ cv4,
        const unsigned short* __restrict__ W0h,
        const float* __restrict__ W1,
        const float* __restrict__ eps0,
        float* __restrict__ g) {
    __shared__ float W1s[D_DIM * C_CLS];
    for (int i = threadIdx.x; i < D_DIM * C_CLS; i += blockDim.x) W1s[i] = W1[i];
    __syncthreads();

    const int lane = threadIdx.x & 63;
    const int n = __builtin_amdgcn_readfirstlane(blockIdx.x * 4 + (threadIdx.x >> 6));
    if (n >= N_NODES) return;
    const float s0 = 0.1f * (1.0f + eps0[0]);
    const bool act = (lane < 50);
    const uint2* __restrict__ F = (const uint2*)W0h;

    const int2 seg = rowseg[n];
    const int beg  = seg.x;
    const int endp = seg.x + seg.y;
    float a0 = 0.f, a1 = 0.f, a2 = 0.f, a3 = 0.f;

    int e = beg;
    for (; e + 8 <= endp; e += 8) {
        unsigned w0 = cv4[e],     w1 = cv4[e + 1], w2 = cv4[e + 2], w3 = cv4[e + 3];
        unsigned w4 = cv4[e + 4], w5 = cv4[e + 5], w6 = cv4[e + 6], w7 = cv4[e + 7];
        if (act) {
            uint2 u0 = F[(size_t)(w0 >> 16) * 50 + lane];
            uint2 u1 = F[(size_t)(w1 >> 16) * 50 + lane];
            uint2 u2 = F[(size_t)(w2 >> 16) * 50 + lane];
            uint2 u3 = F[(size_t)(w3 >> 16) * 50 + lane];
            uint2 u4 = F[(size_t)(w4 >> 16) * 50 + lane];
            uint2 u5 = F[(size_t)(w5 >> 16) * 50 + lane];
            uint2 u6 = F[(size_t)(w6 >> 16) * 50 + lane];
            uint2 u7 = F[(size_t)(w7 >> 16) * 50 + lane];
            float v0 = __uint_as_float(w0 << 16), v1 = __uint_as_float(w1 << 16);
            float v2 = __uint_as_float(w2 << 16), v3 = __uint_as_float(w3 << 16);
            float v4 = __uint_as_float(w4 << 16), v5 = __uint_as_float(w5 << 16);
            float v6 = __uint_as_float(w6 << 16), v7 = __uint_as_float(w7 << 16);
            a0 += v0 * bf_lo(u0.x) + v1 * bf_lo(u1.x) + v2 * bf_lo(u2.x) + v3 * bf_lo(u3.x)
                + v4 * bf_lo(u4.x) + v5 * bf_lo(u5.x) + v6 * bf_lo(u6.x) + v7 * bf_lo(u7.x);
            a1 += v0 * bf_hi(u0.x) + v1 * bf_hi(u1.x) + v2 * bf_hi(u2.x) + v3 * bf_hi(u3.x)
                + v4 * bf_hi(u4.x) + v5 * bf_hi(u5.x) + v6 * bf_hi(u6.x) + v7 * bf_hi(u7.x);
            a2 += v0 * bf_lo(u0.y) + v1 * bf_lo(u1.y) + v2 * bf_lo(u2.y) + v3 * bf_lo(u3.y)
                + v4 * bf_lo(u4.y) + v5 * bf_lo(u5.y) + v6 * bf_lo(u6.y) + v7 * bf_lo(u7.y);
            a3 += v0 * bf_hi(u0.y) + v1 * bf_hi(u1.y) + v2 * bf_hi(u2.y) + v3 * bf_hi(u3.y)
                + v4 * bf_hi(u4.y) + v5 * bf_hi(u5.y) + v6 * bf_hi(u6.y) + v7 * bf_hi(u7.y);
        }
    }
    for (; e + 4 <= endp; e += 4) {
        unsigned w0 = cv4[e], w1 = cv4[e + 1], w2 = cv4[e + 2], w3 = cv4[e + 3];
        if (act) {
            uint2 u0 = F[(size_t)(w0 >> 16) * 50 + lane];
            uint2 u1 = F[(size_t)(w1 >> 16) * 50 + lane];
            uint2 u2 = F[(size_t)(w2 >> 16) * 50 + lane];
            uint2 u3 = F[(size_t)(w3 >> 16) * 50 + lane];
            float v0 = __uint_as_float(w0 << 16), v1 = __uint_as_float(w1 << 16);
            float v2 = __uint_as_float(w2 << 16), v3 = __uint_as_float(w3 << 16);
            a0 += v0 * bf_lo(u0.x) + v1 * bf_lo(u1.x) + v2 * bf_lo(u2.x) + v3 * bf_lo(u3.x);
            a1 += v0 * bf_hi(u0.x) + v1 * bf_hi(u1.x) + v2 * bf_hi(u2.x) + v3 * bf_hi(u3.x);
            a2 += v0 * bf_lo(u0.y) + v1 * bf_lo(u1.y) + v2 * bf_lo(u2.y) + v3 * bf_lo(u3.y);
            a3 += v0 * bf_hi(u0.y) + v1 * bf_hi(u1.y) + v2 * bf_hi(u2.y) + v3 * bf_hi(u3.y);
        }
    }
    for (; e < endp; ++e) {
        unsigned w = cv4[e];
        if (act) {
            uint2 u = F[(size_t)(w >> 16) * 50 + lane];
            float v = __uint_as_float(w << 16);
            a0 += v * bf_lo(u.x);
            a1 += v * bf_hi(u.x);
            a2 += v * bf_lo(u.y);
            a3 += v * bf_hi(u.y);
        }
    }

    float o[C_CLS];
#pragma unroll
    for (int k = 0; k < C_CLS; ++k) o[k] = 0.f;

    if (act) {
        uint2 w = F[(size_t)n * 50 + lane];
        a0 = fmaxf(a0 + s0 * bf_lo(w.x), 0.f);
        a1 = fmaxf(a1 + s0 * bf_hi(w.x), 0.f);
        a2 = fmaxf(a2 + s0 * bf_lo(w.y), 0.f);
        a3 = fmaxf(a3 + s0 * bf_hi(w.y), 0.f);
        const int d = lane * 4;
#pragma unroll
        for (int k = 0; k < C_CLS; ++k) {
            o[k] = a0 * W1s[(d + 0) * C_CLS + k]
                 + a1 * W1s[(d + 1) * C_CLS + k]
                 + a2 * W1s[(d + 2) * C_CLS + k]
                 + a3 * W1s[(d + 3) * C_CLS + k];
        }
    }

#pragma unroll
    for (int k = 0; k < C_CLS; ++k) {
        for (int off = 32; off > 0; off >>= 1)
            o[k] += __shfl_xor(o[k], off, 64);
    }

    if (lane == 0) {
        float* gp = g + (size_t)n * C_CLS;
#pragma unroll
        for (int k = 0; k < C_CLS; ++k) gp[k] = o[k];
    }
}

// ---------------------------------------------------------------------------
// Light layer 1 (r13-proven, rowseg + unroll-2):
//   out[n,:] = sum_e v_e * g[c_e,:] + s1 * g[n,:]
// ---------------------------------------------------------------------------
__global__ __launch_bounds__(256) void spmm_layer1_light_kernel(
        const int2* __restrict__ rowseg,
        const unsigned* __restrict__ cv4,
        const float* __restrict__ g,
        const float* __restrict__ eps1,
        float* __restrict__ out) {
    const int lane = threadIdx.x & 63;
    const int n = __builtin_amdgcn_readfirstlane(blockIdx.x * 4 + (threadIdx.x >> 6));
    if (n >= N_NODES) return;
    const int grp = lane / 10;          // 0..5 active, 6 for lanes 60-63 (idle)
    const int d   = lane - grp * 10;    // 0..9
    const float s1 = 0.1f * (1.0f + eps1[0]);

    const int2 seg = rowseg[n];
    const int beg  = seg.x;
    const int endp = seg.x + seg.y;
    float acc = 0.f;

    for (int base = beg; base < endp; base += 12) {
        if (grp < 6) {
            int ea = base + grp;
            int eb = base + 6 + grp;
            unsigned pa = (ea < endp) ? cv4[ea] : 0u;
            unsigned pb = (eb < endp) ? cv4[eb] : 0u;
            if (ea < endp)
                acc += __uint_as_float(pa << 16) * g[(size_t)(pa >> 16) * C_CLS + d];
            if (eb < endp)
                acc += __uint_as_float(pb << 16) * g[(size_t)(pb >> 16) * C_CLS + d];
        }
    }

    float t;
    t = __shfl(acc, lane + 10, 64); if (lane < 50) acc += t;
    t = __shfl(acc, lane + 20, 64); if (lane < 30) acc += t;
    t = __shfl(acc, lane + 40, 64); if (lane < 10) acc += t;

    if (lane < 10) {
        out[(size_t)n * C_CLS + d] = acc + s1 * g[(size_t)n * C_CLS + d];
    }
}

// ---------------------------------------------------------------------------
extern "C" void kernel_launch(void* const* d_in, const int* in_sizes, int n_in,
                              void* d_out, int out_size, void* d_ws, size_t ws_size,
                              hipStream_t stream) {
    // setup_inputs order: x, rows0, cols0, vals0, rows1, cols1, vals1, W0, W1, eps0, eps1
    const int*   rows0 = (const int*)d_in[1];
    const int*   cols0 = (const int*)d_in[2];
    const float* vals0 = (const float*)d_in[3];
    const int*   rows1 = (const int*)d_in[4];
    const int*   cols1 = (const int*)d_in[5];
    const float* vals1 = (const float*)d_in[6];
    const float* W0    = (const float*)d_in[7];
    const float* W1    = (const float*)d_in[8];
    const float* eps0  = (const float*)d_in[9];
    const float* eps1  = (const float*)d_in[10];
    float* out = (float*)d_out;

    char* ws = (char*)d_ws;
    size_t off = 0;
    auto alloc = [&](size_t bytes) {
        void* p = ws + off;
        off += (bytes + 255) & ~(size_t)255;
        return p;
    };
    unsigned short* W0h = (unsigned short*)alloc((size_t)N_NODES * D_DIM * 2);  // 20 MB
    float* g      = (float*)alloc((size_t)N_NODES * C_CLS * 4);                 // 2 MB
    int2* rowseg  = (int2*)alloc((size_t)N_NODES * 8);                          // 400 KB
    int* bcur     = (int*)alloc((size_t)(NB_BUCKET + 1) * 4);                   // +ticket
    unsigned* cv4 = (unsigned*)alloc((size_t)E2 * 4);                           // 6.4 MB
    int2* stage   = (int2*)alloc((size_t)NB_BUCKET * CAP * 8);                  // 19.3 MB
    int* ticket   = bcur + NB_BUCKET;
    (void)ws_size;

    hipMemsetAsync(bcur, 0, (size_t)(NB_BUCKET + 1) * 4, stream);
    convert_scatter_kernel<<<NB_SCATTER + NB_CONV, 256, 0, stream>>>(
        W0, W0h, rows0, cols0, vals0, rows1, cols1, vals1, bcur, stage);
    build_csr_kernel<<<NB_BUCKET, 256, 0, stream>>>(bcur, stage, ticket, rowseg, cv4);

    const int spmm_grid = (N_NODES + 3) / 4;   // 4 waves/block, 1 wave per node
    spmm_layer0_fused_kernel<<<spmm_grid, 256, 0, stream>>>(
        rowseg, cv4, W0h, W1, eps0, g);
    spmm_layer1_light_kernel<<<spmm_grid, 256, 0, stream>>>(
        rowseg, cv4, g, eps1, out);
}